// Round 1
// baseline (330.573 us; speedup 1.0000x reference)
//
#include <hip/hip_runtime.h>
#include <hip/hip_bf16.h>
#include <math.h>

#define NB 8
#define NN 512
#define NC 256
#define HID 32

// ---------------------------------------------------------------------------
// Kernel 1: xa = x @ ew1[:256], xb = x @ ew1[256:] + eb1   (eb1 folded here)
// block = one row (b*N+i), 64 threads: 32 for xa cols, 32 for xb cols
// ---------------------------------------------------------------------------
__global__ __launch_bounds__(64) void edge_xaxb(
    const float* __restrict__ x, const float* __restrict__ ew1,
    const float* __restrict__ eb1, float* __restrict__ xa, float* __restrict__ xb)
{
    __shared__ float xrow[NC];
    int row = blockIdx.x;
    const float* xr = x + (size_t)row * NC;
    for (int c = threadIdx.x; c < NC; c += 64) xrow[c] = xr[c];
    __syncthreads();
    int k = threadIdx.x & 31;
    int half = threadIdx.x >> 5;
    const float* w = ew1 + (size_t)half * NC * HID + k;
    float acc = 0.f;
#pragma unroll 8
    for (int c = 0; c < NC; ++c) acc = fmaf(xrow[c], w[c * HID], acc);
    if (half) xb[(size_t)row * HID + k] = acc + eb1[k];
    else      xa[(size_t)row * HID + k] = acc;
}

// ---------------------------------------------------------------------------
// Kernel 2: A_pred[b,i,j] = (i!=j && valid) ? exp(0.5*(s_ij+s_ji)+eb2) : 0
//   s_ij = sum_k relu(xa[i,k]+xb[j,k]) * ew2[k]   (eb1 already inside xb)
// 32x32 tile per block, 256 threads, 4 elems/thread.
// ---------------------------------------------------------------------------
__global__ __launch_bounds__(256) void edge_scores(
    const float* __restrict__ xa, const float* __restrict__ xb,
    const float* __restrict__ ew2, const float* __restrict__ eb2,
    const float* __restrict__ mask, float* __restrict__ AP)
{
    __shared__ float aI[32][33], bJ[32][33], aJ[32][33], bI[32][33];
    __shared__ float w2[32];
    int b  = blockIdx.z;
    int i0 = blockIdx.x * 32, j0 = blockIdx.y * 32;
    const float* xab = xa + (size_t)b * NN * HID;
    const float* xbb = xb + (size_t)b * NN * HID;
    int t = threadIdx.x;
    if (t < 32) w2[t] = ew2[t];
#pragma unroll
    for (int p = 0; p < 4; ++p) {
        int e = t + p * 256; int r = e >> 5, c = e & 31;
        aI[r][c] = xab[(size_t)(i0 + r) * HID + c];
        bJ[r][c] = xbb[(size_t)(j0 + r) * HID + c];
        aJ[r][c] = xab[(size_t)(j0 + r) * HID + c];
        bI[r][c] = xbb[(size_t)(i0 + r) * HID + c];
    }
    __syncthreads();
    float eb2v = eb2[0];
#pragma unroll
    for (int p = 0; p < 4; ++p) {
        int e = t + p * 256; int ti = e >> 5, tj = e & 31;
        int i = i0 + ti, j = j0 + tj;
        float sij = 0.f, sji = 0.f;
#pragma unroll
        for (int k = 0; k < 32; ++k) {
            sij = fmaf(fmaxf(aI[ti][k] + bJ[tj][k], 0.f), w2[k], sij);
            sji = fmaf(fmaxf(aJ[tj][k] + bI[ti][k], 0.f), w2[k], sji);
        }
        bool ok = (i != j) && (mask[b * NN + i] > 0.f) && (mask[b * NN + j] > 0.f);
        float val = ok ? expf(0.5f * (sij + sji) + eb2v) : 0.f;
        AP[((size_t)b * NN + i) * NN + j] = val;
    }
}

// ---------------------------------------------------------------------------
// Kernel 3: degree vectors. D[b,k] = (sum_i A_hat[b,i,k] + 1e-5)^-0.5
// axis=1 sum == COLUMN sums (A is not symmetric!). +1 for the identity diag.
// z=0: from A -> d0 ; z=1: from AP -> d1
// ---------------------------------------------------------------------------
__global__ __launch_bounds__(256) void colsum_deg(
    const float* __restrict__ A, const float* __restrict__ AP,
    float* __restrict__ d0, float* __restrict__ d1)
{
    int which = blockIdx.z;
    const float* src = which ? AP : A;
    int b = blockIdx.y;
    int k = blockIdx.x * 256 + threadIdx.x;
    const float* col = src + (size_t)b * NN * NN + k;
    float s = 0.f;
    for (int i = 0; i < NN; ++i) s += col[(size_t)i * NN];
    s += 1.0f;                     // identity diagonal of A_hat
    float d = 1.0f / sqrtf(s + 1e-5f);
    (which ? d1 : d0)[b * NN + k] = d;
}

// ---------------------------------------------------------------------------
// Kernel 4: materialize Laplacians.
// z=0: L0[b,i,j] = d0[i]*(A+I)*d0[j]   z=1: AP <- d1[i]*(AP+I)*d1[j] in place
// ---------------------------------------------------------------------------
__global__ __launch_bounds__(256) void make_lap(
    const float* __restrict__ A, float* __restrict__ L0,
    float* __restrict__ AP, const float* __restrict__ d0,
    const float* __restrict__ d1)
{
    size_t idx = (size_t)blockIdx.x * 256 + threadIdx.x;   // over B*N*N
    int b = (int)(idx >> 18);
    int rem = (int)(idx & (NN * NN - 1));
    int i = rem >> 9, j = rem & (NN - 1);
    if (blockIdx.y == 0) {
        float v = A[idx] + (i == j ? 1.f : 0.f);
        L0[idx] = d0[b * NN + i] * v * d0[b * NN + j];
    } else {
        float v = AP[idx] + (i == j ? 1.f : 0.f);
        AP[idx] = d1[b * NN + i] * v * d1[b * NN + j];
    }
}

// ---------------------------------------------------------------------------
// Kernel 5: XH[:, lap*Cin : (lap+1)*Cin] = L @ H  (per batch, per laplacian)
// BM=64 BN=64 BK=32, 256 threads, 4x4 per thread. K = N = 512.
// ---------------------------------------------------------------------------
__global__ __launch_bounds__(256) void lap_gemm(
    const float* __restrict__ L0, const float* __restrict__ L1,
    const float* __restrict__ H, float* __restrict__ XH, int Cin)
{
    int z = blockIdx.z; int b = z >> 1; int lap = z & 1;
    const float* L  = (lap ? L1 : L0) + (size_t)b * NN * NN;
    const float* Hb = H + (size_t)b * NN * Cin;
    float* outp = XH + (size_t)b * NN * (2 * Cin) + (size_t)lap * Cin;
    int i0 = blockIdx.x * 64, j0 = blockIdx.y * 64;
    __shared__ float sL[32][65];   // [k][m]
    __shared__ float sH[32][65];   // [k][n]
    float acc[4][4] = {};
    int tx = threadIdx.x & 15, ty = threadIdx.x >> 4;
    int lc = threadIdx.x & 31, lr = threadIdx.x >> 5;   // L-tile loader
    int hc = threadIdx.x & 63, hr = threadIdx.x >> 6;   // H-tile loader
    for (int k0 = 0; k0 < NN; k0 += 32) {
#pragma unroll
        for (int p = 0; p < 8; ++p)
            sL[lc][lr + p * 8] = L[(size_t)(i0 + lr + p * 8) * NN + k0 + lc];
#pragma unroll
        for (int p = 0; p < 8; ++p)
            sH[hr + p * 4][hc] = Hb[(size_t)(k0 + hr + p * 4) * Cin + j0 + hc];
        __syncthreads();
#pragma unroll
        for (int k = 0; k < 32; ++k) {
            float a[4], bb[4];
#pragma unroll
            for (int m = 0; m < 4; ++m) a[m] = sL[k][ty * 4 + m];
#pragma unroll
            for (int n = 0; n < 4; ++n) bb[n] = sH[k][tx * 4 + n];
#pragma unroll
            for (int m = 0; m < 4; ++m)
#pragma unroll
                for (int n = 0; n < 4; ++n)
                    acc[m][n] = fmaf(a[m], bb[n], acc[m][n]);
        }
        __syncthreads();
    }
#pragma unroll
    for (int m = 0; m < 4; ++m)
#pragma unroll
        for (int n = 0; n < 4; ++n)
            outp[(size_t)(i0 + ty * 4 + m) * (2 * Cin) + j0 + tx * 4 + n] = acc[m][n];
}

// ---------------------------------------------------------------------------
// Kernel 6: Hout = relu((XH @ W + bias) * mask_row)
// XH: (4096 x K2) row-major, W: (K2 x 64), Hout: (4096 x 64)
// ---------------------------------------------------------------------------
__global__ __launch_bounds__(256) void dense_relu(
    const float* __restrict__ XH, const float* __restrict__ W,
    const float* __restrict__ bias, const float* __restrict__ mask,
    float* __restrict__ Hout, int K2)
{
    int r0 = blockIdx.x * 64;
    __shared__ float sX[32][65];   // [k][m]
    __shared__ float sW[32][65];   // [k][n]
    float acc[4][4] = {};
    int tx = threadIdx.x & 15, ty = threadIdx.x >> 4;
    int lc = threadIdx.x & 31, lr = threadIdx.x >> 5;
    int hc = threadIdx.x & 63, hr = threadIdx.x >> 6;
    for (int k0 = 0; k0 < K2; k0 += 32) {
#pragma unroll
        for (int p = 0; p < 8; ++p)
            sX[lc][lr + p * 8] = XH[(size_t)(r0 + lr + p * 8) * K2 + k0 + lc];
#pragma unroll
        for (int p = 0; p < 8; ++p)
            sW[hr + p * 4][hc] = W[(size_t)(k0 + hr + p * 4) * 64 + hc];
        __syncthreads();
#pragma unroll
        for (int k = 0; k < 32; ++k) {
            float a[4], bb[4];
#pragma unroll
            for (int m = 0; m < 4; ++m) a[m] = sX[k][ty * 4 + m];
#pragma unroll
            for (int n = 0; n < 4; ++n) bb[n] = sW[k][tx * 4 + n];
#pragma unroll
            for (int m = 0; m < 4; ++m)
#pragma unroll
                for (int n = 0; n < 4; ++n)
                    acc[m][n] = fmaf(a[m], bb[n], acc[m][n]);
        }
        __syncthreads();
    }
#pragma unroll
    for (int m = 0; m < 4; ++m) {
        int r = r0 + ty * 4 + m;
        float mv = mask[r];
#pragma unroll
        for (int n = 0; n < 4; ++n) {
            int o = tx * 4 + n;
            float v = (acc[m][n] + bias[o]) * mv;
            Hout[(size_t)r * 64 + o] = fmaxf(v, 0.f);
        }
    }
}

// ---------------------------------------------------------------------------
// Kernel 7: g[b,o] = max_i H[b,i,o]; out[b,t] = sum_o g[o]*fcw[o,t] + fcb[t]
// ---------------------------------------------------------------------------
__global__ __launch_bounds__(256) void final_fc(
    const float* __restrict__ H, const float* __restrict__ fcw,
    const float* __restrict__ fcb, float* __restrict__ out)
{
    __shared__ float red[4][64];
    __shared__ float g[64];
    int b = blockIdx.x;
    int o = threadIdx.x & 63, seg = threadIdx.x >> 6;
    const float* Hb = H + (size_t)b * NN * 64;
    float mx = -INFINITY;
    for (int i = seg; i < NN; i += 4) mx = fmaxf(mx, Hb[(size_t)i * 64 + o]);
    red[seg][o] = mx;
    __syncthreads();
    if (seg == 0)
        g[o] = fmaxf(fmaxf(red[0][o], red[1][o]), fmaxf(red[2][o], red[3][o]));
    __syncthreads();
    if (threadIdx.x < 2) {
        float acc = fcb[threadIdx.x];
        for (int k = 0; k < 64; ++k) acc = fmaf(g[k], fcw[k * 2 + threadIdx.x], acc);
        out[b * 2 + threadIdx.x] = acc;
    }
}

extern "C" void kernel_launch(void* const* d_in, const int* in_sizes, int n_in,
                              void* d_out, int out_size, void* d_ws, size_t ws_size,
                              hipStream_t stream)
{
    const float* x    = (const float*)d_in[0];
    const float* A    = (const float*)d_in[1];
    const float* mask = (const float*)d_in[2];
    const float* ew1  = (const float*)d_in[3];
    const float* eb1  = (const float*)d_in[4];
    const float* ew2  = (const float*)d_in[5];
    const float* eb2  = (const float*)d_in[6];
    const float* gw0  = (const float*)d_in[7];
    const float* gb0  = (const float*)d_in[8];
    const float* gw1  = (const float*)d_in[9];
    const float* gb1  = (const float*)d_in[10];
    const float* gw2  = (const float*)d_in[11];
    const float* gb2  = (const float*)d_in[12];
    const float* fcw  = (const float*)d_in[13];
    const float* fcb  = (const float*)d_in[14];
    float* out = (float*)d_out;
    float* ws  = (float*)d_ws;

    // workspace layout (floats)
    float* xa = ws;                    // 131072
    float* xb = ws + 131072;           // 131072
    float* AP = ws + 262144;           // 2097152  (A_pred, becomes L1 in place)
    float* L0 = ws + 2359296;          // 2097152
    float* d0 = ws + 4456448;          // 4096
    float* d1 = ws + 4460544;          // 4096
    float* xh = ws + 4464640;          // 2097152  (max 4096 x 512)
    float* hA = ws + 6561792;          // 262144
    float* hB = ws + 6823936;          // 262144
    // total 7086080 floats = 28.3 MB

    edge_xaxb  <<<NB * NN, 64, 0, stream>>>(x, ew1, eb1, xa, xb);
    edge_scores<<<dim3(16, 16, NB), 256, 0, stream>>>(xa, xb, ew2, eb2, mask, AP);
    colsum_deg <<<dim3(2, NB, 2), 256, 0, stream>>>(A, AP, d0, d1);
    make_lap   <<<dim3(NB * NN * NN / 256, 2), 256, 0, stream>>>(A, L0, AP, d0, d1);

    // layer 0: Cin = 256, K2 = 512
    lap_gemm  <<<dim3(8, 4, 2 * NB), 256, 0, stream>>>(L0, AP, x, xh, 256);
    dense_relu<<<dim3(64), 256, 0, stream>>>(xh, gw0, gb0, mask, hA, 512);
    // layer 1: Cin = 64, K2 = 128
    lap_gemm  <<<dim3(8, 1, 2 * NB), 256, 0, stream>>>(L0, AP, hA, xh, 64);
    dense_relu<<<dim3(64), 256, 0, stream>>>(xh, gw1, gb1, mask, hB, 128);
    // layer 2
    lap_gemm  <<<dim3(8, 1, 2 * NB), 256, 0, stream>>>(L0, AP, hB, xh, 64);
    dense_relu<<<dim3(64), 256, 0, stream>>>(xh, gw2, gb2, mask, hA, 128);

    final_fc<<<NB, 256, 0, stream>>>(hA, fcw, fcb, out);
}

// Round 2
// 236.560 us; speedup vs baseline: 1.3974x; 1.3974x over previous
//
#include <hip/hip_runtime.h>
#include <hip/hip_bf16.h>
#include <math.h>

#define NB 8
#define NN 512
#define NC 256
#define HID 32

// ---------------------------------------------------------------------------
// Kernel 1: xab[row, 0:32] = x@ew1[:256]; xab[row,32:64] = x@ew1[256:] + eb1
// M=4096, N=64, K=256. BM=16, BN=64, 256 blocks x 256 threads.
// ---------------------------------------------------------------------------
__global__ __launch_bounds__(256) void xaxb_gemm(
    const float* __restrict__ x, const float* __restrict__ ew1,
    const float* __restrict__ eb1, float* __restrict__ xab)
{
    __shared__ float sX[32][17];   // [k][m]  (transposed, BM=16 -> stride 17)
    __shared__ float sW[32][68];   // [k][n]
    int r0 = blockIdx.x * 16;
    int t = threadIdx.x;
    int tx = t & 15, ty = t >> 4;          // c4 = tx*4, row = ty
    float acc[4] = {0.f, 0.f, 0.f, 0.f};
    for (int k0 = 0; k0 < NC; k0 += 32) {
        {   // X tile: 16 rows x 32 k
            int kk = (t & 15) * 2, r = t >> 4;
            const float* src = x + (size_t)(r0 + r) * NC + k0 + kk;
            float2 v = *(const float2*)src;
            sX[kk][r] = v.x; sX[kk + 1][r] = v.y;
        }
        {   // W tile: 32 k x 64 n (n<32: wa, n>=32: wb)
            int c4 = (t & 15) * 4;
            int half = c4 >> 5;
            int cc = c4 & 31;
#pragma unroll
            for (int rr = 0; rr < 2; ++rr) {
                int kk = (t >> 4) + rr * 16;
                const float* w = ew1 + (size_t)(half * NC + k0 + kk) * HID + cc;
                *(float4*)&sW[kk][c4] = *(const float4*)w;
            }
        }
        __syncthreads();
#pragma unroll
        for (int k = 0; k < 32; ++k) {
            float a = sX[k][ty];
            float4 w = *(const float4*)&sW[k][tx * 4];
            acc[0] = fmaf(a, w.x, acc[0]);
            acc[1] = fmaf(a, w.y, acc[1]);
            acc[2] = fmaf(a, w.z, acc[2]);
            acc[3] = fmaf(a, w.w, acc[3]);
        }
        __syncthreads();
    }
    int c4 = tx * 4;
    float4 o;
    o.x = acc[0]; o.y = acc[1]; o.z = acc[2]; o.w = acc[3];
    if (c4 >= 32) {
        o.x += eb1[c4 - 32]; o.y += eb1[c4 - 31];
        o.z += eb1[c4 - 30]; o.w += eb1[c4 - 29];
    }
    *(float4*)&xab[(size_t)(r0 + ty) * 64 + c4] = o;
}

// ---------------------------------------------------------------------------
// Kernel 2: A_pred (raw, symmetric, zero diag). Triangle-tiled: block handles
// tile-pair (X,Y), X<=Y, writes both (i,j) and (j,i). 136 pairs x 8 batches.
// ---------------------------------------------------------------------------
__global__ __launch_bounds__(256) void edge_scores(
    const float* __restrict__ xab, const float* __restrict__ ew2,
    const float* __restrict__ eb2, const float* __restrict__ mask,
    float* __restrict__ AP)
{
    __shared__ float sI[32][65], sJ[32][65];   // rows of xab (64 cols), stride 65
    __shared__ float w2[32];
    int b = blockIdx.z;
    int p = blockIdx.x;
    int X = 0;
    while ((X + 1) * 16 - ((X + 1) * X) / 2 <= p) ++X;
    int Y = X + (p - (X * 16 - (X * (X - 1)) / 2));
    int i0 = X * 32, j0 = Y * 32;
    int t = threadIdx.x;
    if (t < 32) w2[t] = ew2[t];
    {
        int c4 = (t & 15) * 4;
#pragma unroll
        for (int rr = 0; rr < 2; ++rr) {
            int r = (t >> 4) + rr * 16;
            float4 vi = *(const float4*)(xab + ((size_t)(b * NN + i0 + r)) * 64 + c4);
            float4 vj = *(const float4*)(xab + ((size_t)(b * NN + j0 + r)) * 64 + c4);
            sI[r][c4] = vi.x; sI[r][c4 + 1] = vi.y; sI[r][c4 + 2] = vi.z; sI[r][c4 + 3] = vi.w;
            sJ[r][c4] = vj.x; sJ[r][c4 + 1] = vj.y; sJ[r][c4 + 2] = vj.z; sJ[r][c4 + 3] = vj.w;
        }
    }
    __syncthreads();
    float eb2v = eb2[0];
#pragma unroll
    for (int pz = 0; pz < 4; ++pz) {
        int e = t + pz * 256;
        int ti = e >> 5, tj = e & 31;
        int i = i0 + ti, j = j0 + tj;
        float sij = 0.f, sji = 0.f;
#pragma unroll
        for (int k = 0; k < 32; ++k) {
            sij = fmaf(fmaxf(sI[ti][k] + sJ[tj][32 + k], 0.f), w2[k], sij);
            sji = fmaf(fmaxf(sJ[tj][k] + sI[ti][32 + k], 0.f), w2[k], sji);
        }
        bool ok = (i != j) && (mask[b * NN + i] > 0.f) && (mask[b * NN + j] > 0.f);
        float val = ok ? expf(0.5f * (sij + sji) + eb2v) : 0.f;
        AP[((size_t)b * NN + i) * NN + j] = val;
        AP[((size_t)b * NN + j) * NN + i] = val;
    }
}

// ---------------------------------------------------------------------------
// Kernel 3a: partial column sums (axis=1 of A is column sums) via atomics.
// grid (2, 64, 2): x = col-half, y = b*8+rowslice, z = which matrix.
// ---------------------------------------------------------------------------
__global__ __launch_bounds__(256) void colsum_part(
    const float* __restrict__ A, const float* __restrict__ AP,
    float* __restrict__ dsum)
{
    int which = blockIdx.z;
    const float* src = which ? AP : A;
    int b = blockIdx.y >> 3, rs = blockIdx.y & 7;
    int k = blockIdx.x * 256 + threadIdx.x;
    const float* col = src + ((size_t)b * NN + rs * 64) * NN + k;
    float s = 0.f;
#pragma unroll 8
    for (int i = 0; i < 64; ++i) s += col[(size_t)i * NN];
    atomicAdd(&dsum[which * (NB * NN) + b * NN + k], s);
}

// Kernel 3b: dsum <- (sum + 1 (diag) + 1e-5)^-0.5 in place, 8192 elems
__global__ __launch_bounds__(256) void deg_final(float* __restrict__ dsum)
{
    int idx = blockIdx.x * 256 + threadIdx.x;
    float s = dsum[idx];
    dsum[idx] = 1.0f / sqrtf(s + 1.0f + 1e-5f);
}

// ---------------------------------------------------------------------------
// Kernel 4: P[row, c] = d_lap[row] * (h @ W')[row, c]
//   W'[k][c] = c<64 ? gw[k][c] : gw[Cin+k][c-64]   (Wtop | Wbot)
// M=4096, N=128, K=Cin. BM=16, 256 blocks x 256 threads, 8 out/thread.
// ---------------------------------------------------------------------------
__global__ __launch_bounds__(256) void pre_gemm(
    const float* __restrict__ h, const float* __restrict__ gw,
    const float* __restrict__ dsum, float* __restrict__ P, int Cin)
{
    __shared__ float sH[32][17];    // [k][m]
    __shared__ float sW[32][132];   // [k][n]  n in [0,128)
    int r0 = blockIdx.x * 16;
    int t = threadIdx.x;
    int tx = t & 31, ty = t >> 5;   // c4 = tx*4, rows = ty*2 + {0,1}
    float acc0[4] = {0.f, 0.f, 0.f, 0.f};
    float acc1[4] = {0.f, 0.f, 0.f, 0.f};
    for (int k0 = 0; k0 < Cin; k0 += 32) {
        {   // H tile 16 x 32
            int kk = (t & 15) * 2, r = t >> 4;
            const float* src = h + (size_t)(r0 + r) * Cin + k0 + kk;
            float2 v = *(const float2*)src;
            sH[kk][r] = v.x; sH[kk + 1][r] = v.y;
        }
        {   // W tile 32 x 128
            int c4 = (t & 31) * 4;
            int half = c4 >> 6;
            int cc = c4 & 63;
#pragma unroll
            for (int rr = 0; rr < 4; ++rr) {
                int kk = (t >> 5) + rr * 8;
                const float* w = gw + (size_t)(half * Cin + k0 + kk) * 64 + cc;
                *(float4*)&sW[kk][c4] = *(const float4*)w;
            }
        }
        __syncthreads();
#pragma unroll
        for (int k = 0; k < 32; ++k) {
            float a0 = sH[k][ty * 2];
            float a1 = sH[k][ty * 2 + 1];
            float4 w = *(const float4*)&sW[k][tx * 4];
            acc0[0] = fmaf(a0, w.x, acc0[0]); acc0[1] = fmaf(a0, w.y, acc0[1]);
            acc0[2] = fmaf(a0, w.z, acc0[2]); acc0[3] = fmaf(a0, w.w, acc0[3]);
            acc1[0] = fmaf(a1, w.x, acc1[0]); acc1[1] = fmaf(a1, w.y, acc1[1]);
            acc1[2] = fmaf(a1, w.z, acc1[2]); acc1[3] = fmaf(a1, w.w, acc1[3]);
        }
        __syncthreads();
    }
    int c4 = tx * 4;
    const float* drow = dsum + ((c4 >= 64) ? (NB * NN) : 0);
#pragma unroll
    for (int r = 0; r < 2; ++r) {
        int row = r0 + ty * 2 + r;          // == b*512 + i
        float d = drow[row];
        float* ap = (r == 0) ? acc0 : acc1;
        float4 o;
        o.x = d * ap[0]; o.y = d * ap[1]; o.z = d * ap[2]; o.w = d * ap[3];
        *(float4*)&P[(size_t)row * 128 + c4] = o;
    }
}

// ---------------------------------------------------------------------------
// Kernel 5: fused dual-Laplacian GEMM + epilogue.
// Hout[b,i,c] = relu( (d0[i]*(sum_k A[i,k]*P[k,c]    + P[i,c])
//                    + d1[i]*(sum_k AP[i,k]*P[k,64+c]+ P[i,64+c]) + bias[c]) * m[i] )
// grid (32, 8): BM=16 rows, BN=64 cols, both laps per thread. BK=64.
// ---------------------------------------------------------------------------
__global__ __launch_bounds__(256) void fused_lap(
    const float* __restrict__ A, const float* __restrict__ AP,
    const float* __restrict__ P, const float* __restrict__ dsum,
    const float* __restrict__ bias, const float* __restrict__ mask,
    float* __restrict__ Hout)
{
    __shared__ float sA[2][64][17];   // [lap][k][m]
    __shared__ float sP[64][132];     // [k][n], n in [0,128)
    int b = blockIdx.y;
    int i0 = blockIdx.x * 16;
    int t = threadIdx.x;
    int tx = t & 15, ty = t >> 4;     // c4 = tx*4, row = ty
    float acc0[4] = {0.f, 0.f, 0.f, 0.f};
    float acc1[4] = {0.f, 0.f, 0.f, 0.f};
    const float* Ab  = A  + (size_t)b * NN * NN;
    const float* APb = AP + (size_t)b * NN * NN;
    for (int k0 = 0; k0 < NN; k0 += 64) {
        {   // A / AP tiles: 16 rows x 64 k, transposed into LDS
            int kk4 = (t & 15) * 4, r = t >> 4;
            float4 va = *(const float4*)(Ab  + (size_t)(i0 + r) * NN + k0 + kk4);
            float4 vb = *(const float4*)(APb + (size_t)(i0 + r) * NN + k0 + kk4);
            sA[0][kk4][r] = va.x; sA[0][kk4 + 1][r] = va.y;
            sA[0][kk4 + 2][r] = va.z; sA[0][kk4 + 3][r] = va.w;
            sA[1][kk4][r] = vb.x; sA[1][kk4 + 1][r] = vb.y;
            sA[1][kk4 + 2][r] = vb.z; sA[1][kk4 + 3][r] = vb.w;
        }
        {   // P tile: 64 rows x 128 cols
            int c4 = (t & 31) * 4, rb = t >> 5;
#pragma unroll
            for (int rr = 0; rr < 8; ++rr) {
                int kk = rb + rr * 8;
                const float* pp = P + ((size_t)(b * NN + k0 + kk)) * 128 + c4;
                *(float4*)&sP[kk][c4] = *(const float4*)pp;
            }
        }
        __syncthreads();
#pragma unroll
        for (int k = 0; k < 64; ++k) {
            float a0 = sA[0][k][ty];
            float a1 = sA[1][k][ty];
            float4 p0 = *(const float4*)&sP[k][tx * 4];
            float4 p1 = *(const float4*)&sP[k][64 + tx * 4];
            acc0[0] = fmaf(a0, p0.x, acc0[0]); acc0[1] = fmaf(a0, p0.y, acc0[1]);
            acc0[2] = fmaf(a0, p0.z, acc0[2]); acc0[3] = fmaf(a0, p0.w, acc0[3]);
            acc1[0] = fmaf(a1, p1.x, acc1[0]); acc1[1] = fmaf(a1, p1.y, acc1[1]);
            acc1[2] = fmaf(a1, p1.z, acc1[2]); acc1[3] = fmaf(a1, p1.w, acc1[3]);
        }
        __syncthreads();
    }
    int row = i0 + ty;
    size_t gr = (size_t)b * NN + row;
    float d0 = dsum[gr], d1 = dsum[NB * NN + gr];
    float mv = mask[gr];
    int c4 = tx * 4;
    float4 p0i = *(const float4*)&P[gr * 128 + c4];
    float4 p1i = *(const float4*)&P[gr * 128 + 64 + c4];
    float4 o;
    o.x = fmaxf((d0 * (acc0[0] + p0i.x) + d1 * (acc1[0] + p1i.x) + bias[c4 + 0]) * mv, 0.f);
    o.y = fmaxf((d0 * (acc0[1] + p0i.y) + d1 * (acc1[1] + p1i.y) + bias[c4 + 1]) * mv, 0.f);
    o.z = fmaxf((d0 * (acc0[2] + p0i.z) + d1 * (acc1[2] + p1i.z) + bias[c4 + 2]) * mv, 0.f);
    o.w = fmaxf((d0 * (acc0[3] + p0i.w) + d1 * (acc1[3] + p1i.w) + bias[c4 + 3]) * mv, 0.f);
    *(float4*)&Hout[gr * 64 + c4] = o;
}

// ---------------------------------------------------------------------------
// Kernel 6: g[b,o] = max_i H[b,i,o]; out[b,t] = sum_o g[o]*fcw[o,t] + fcb[t]
// ---------------------------------------------------------------------------
__global__ __launch_bounds__(256) void final_fc(
    const float* __restrict__ H, const float* __restrict__ fcw,
    const float* __restrict__ fcb, float* __restrict__ out)
{
    __shared__ float red[4][64];
    __shared__ float g[64];
    int b = blockIdx.x;
    int o = threadIdx.x & 63, seg = threadIdx.x >> 6;
    const float* Hb = H + (size_t)b * NN * 64;
    float mx = -INFINITY;
    for (int i = seg; i < NN; i += 4) mx = fmaxf(mx, Hb[(size_t)i * 64 + o]);
    red[seg][o] = mx;
    __syncthreads();
    if (seg == 0)
        g[o] = fmaxf(fmaxf(red[0][o], red[1][o]), fmaxf(red[2][o], red[3][o]));
    __syncthreads();
    if (threadIdx.x < 2) {
        float acc = fcb[threadIdx.x];
        for (int k = 0; k < 64; ++k) acc = fmaf(g[k], fcw[k * 2 + threadIdx.x], acc);
        out[b * 2 + threadIdx.x] = acc;
    }
}

extern "C" void kernel_launch(void* const* d_in, const int* in_sizes, int n_in,
                              void* d_out, int out_size, void* d_ws, size_t ws_size,
                              hipStream_t stream)
{
    const float* x    = (const float*)d_in[0];
    const float* A    = (const float*)d_in[1];
    const float* mask = (const float*)d_in[2];
    const float* ew1  = (const float*)d_in[3];
    const float* eb1  = (const float*)d_in[4];
    const float* ew2  = (const float*)d_in[5];
    const float* eb2  = (const float*)d_in[6];
    const float* gw0  = (const float*)d_in[7];
    const float* gb0  = (const float*)d_in[8];
    const float* gw1  = (const float*)d_in[9];
    const float* gb1  = (const float*)d_in[10];
    const float* gw2  = (const float*)d_in[11];
    const float* gb2  = (const float*)d_in[12];
    const float* fcw  = (const float*)d_in[13];
    const float* fcb  = (const float*)d_in[14];
    float* out = (float*)d_out;
    float* ws  = (float*)d_ws;

    // workspace layout (floats)
    float* xab  = ws;                  // 262144
    float* AP   = ws + 262144;         // 2097152 (raw A_pred)
    float* dsum = ws + 2359296;        // 8192  ([0]=d0 sums->d0, [4096]=d1)
    float* P    = ws + 2367488;        // 524288 (4096 x 128)
    float* hA   = ws + 2891776;        // 262144
    float* hB   = ws + 3153920;        // 262144
    // total 3416064 floats = 13.7 MB

    hipMemsetAsync(dsum, 0, 8192 * sizeof(float), stream);

    xaxb_gemm  <<<256, 256, 0, stream>>>(x, ew1, eb1, xab);
    edge_scores<<<dim3(136, 1, NB), 256, 0, stream>>>(xab, ew2, eb2, mask, AP);
    colsum_part<<<dim3(2, 64, 2), 256, 0, stream>>>(A, AP, dsum);
    deg_final  <<<32, 256, 0, stream>>>(dsum);

    // layer 0
    pre_gemm <<<256, 256, 0, stream>>>(x, gw0, dsum, P, 256);
    fused_lap<<<dim3(32, NB), 256, 0, stream>>>(A, AP, P, dsum, gb0, mask, hA);
    // layer 1
    pre_gemm <<<256, 256, 0, stream>>>(hA, gw1, dsum, P, 64);
    fused_lap<<<dim3(32, NB), 256, 0, stream>>>(A, AP, P, dsum, gb1, mask, hB);
    // layer 2
    pre_gemm <<<256, 256, 0, stream>>>(hB, gw2, dsum, P, 64);
    fused_lap<<<dim3(32, NB), 256, 0, stream>>>(A, AP, P, dsum, gb2, mask, hA);

    final_fc<<<NB, 256, 0, stream>>>(hA, fcw, fcb, out);
}

// Round 3
// 227.101 us; speedup vs baseline: 1.4556x; 1.0416x over previous
//
#include <hip/hip_runtime.h>
#include <hip/hip_bf16.h>
#include <math.h>

#define NB 8
#define NN 512
#define NC 256
#define HID 32

typedef __attribute__((ext_vector_type(8))) short short8;
typedef __attribute__((ext_vector_type(4))) float float4v;
typedef unsigned short ushort_t;

__device__ __forceinline__ ushort_t f2bf(float x) {
    unsigned u = __float_as_uint(x);
    return (ushort_t)((u + 0x7fffu + ((u >> 16) & 1u)) >> 16);
}
__device__ __forceinline__ float bf2f(ushort_t h) {
    return __uint_as_float(((unsigned)h) << 16);
}

// ---------------------------------------------------------------------------
// Kernel 1: xab = x @ [wa|wb] (+eb1 on wb half). Also zeroes dsum (blocks<32).
// ---------------------------------------------------------------------------
__global__ __launch_bounds__(256) void xaxb_gemm(
    const float* __restrict__ x, const float* __restrict__ ew1,
    const float* __restrict__ eb1, float* __restrict__ xab,
    float* __restrict__ dsum)
{
    __shared__ float sX[32][17];
    __shared__ float sW[32][68];
    int t = threadIdx.x;
    if (blockIdx.x < 32) dsum[blockIdx.x * 256 + t] = 0.f;   // zero-init degrees
    int r0 = blockIdx.x * 16;
    int tx = t & 15, ty = t >> 4;
    float acc[4] = {0.f, 0.f, 0.f, 0.f};
    for (int k0 = 0; k0 < NC; k0 += 32) {
        {
            int kk = (t & 15) * 2, r = t >> 4;
            float2 v = *(const float2*)(x + (size_t)(r0 + r) * NC + k0 + kk);
            sX[kk][r] = v.x; sX[kk + 1][r] = v.y;
        }
        {
            int c4 = (t & 15) * 4;
            int half = c4 >> 5, cc = c4 & 31;
#pragma unroll
            for (int rr = 0; rr < 2; ++rr) {
                int kk = (t >> 4) + rr * 16;
                *(float4*)&sW[kk][c4] =
                    *(const float4*)(ew1 + (size_t)(half * NC + k0 + kk) * HID + cc);
            }
        }
        __syncthreads();
#pragma unroll
        for (int k = 0; k < 32; ++k) {
            float a = sX[k][ty];
            float4 w = *(const float4*)&sW[k][tx * 4];
            acc[0] = fmaf(a, w.x, acc[0]); acc[1] = fmaf(a, w.y, acc[1]);
            acc[2] = fmaf(a, w.z, acc[2]); acc[3] = fmaf(a, w.w, acc[3]);
        }
        __syncthreads();
    }
    int c4 = tx * 4;
    float4 o; o.x = acc[0]; o.y = acc[1]; o.z = acc[2]; o.w = acc[3];
    if (c4 >= 32) {
        o.x += eb1[c4 - 32]; o.y += eb1[c4 - 31];
        o.z += eb1[c4 - 30]; o.w += eb1[c4 - 29];
    }
    *(float4*)&xab[(size_t)(r0 + ty) * 64 + c4] = o;
}

// ---------------------------------------------------------------------------
// Kernel 2: edge scores -> AP as bf16 hi/lo, symmetric write via LDS transpose
// ---------------------------------------------------------------------------
__global__ __launch_bounds__(256) void edge_scores(
    const float* __restrict__ xab, const float* __restrict__ ew2,
    const float* __restrict__ eb2, const float* __restrict__ mask,
    ushort_t* __restrict__ APh, ushort_t* __restrict__ APl)
{
    __shared__ float sI[32][65], sJ[32][65];
    __shared__ float sV[32][33];
    __shared__ float w2[32];
    int b = blockIdx.z;
    int p = blockIdx.x;
    int X = 0;
    while ((X + 1) * 16 - ((X + 1) * X) / 2 <= p) ++X;
    int Y = X + (p - (X * 16 - (X * (X - 1)) / 2));
    int i0 = X * 32, j0 = Y * 32;
    int t = threadIdx.x;
    if (t < 32) w2[t] = ew2[t];
    {
        int c4 = (t & 15) * 4;
#pragma unroll
        for (int rr = 0; rr < 2; ++rr) {
            int r = (t >> 4) + rr * 16;
            float4 vi = *(const float4*)(xab + ((size_t)(b * NN + i0 + r)) * 64 + c4);
            float4 vj = *(const float4*)(xab + ((size_t)(b * NN + j0 + r)) * 64 + c4);
            sI[r][c4] = vi.x; sI[r][c4 + 1] = vi.y; sI[r][c4 + 2] = vi.z; sI[r][c4 + 3] = vi.w;
            sJ[r][c4] = vj.x; sJ[r][c4 + 1] = vj.y; sJ[r][c4 + 2] = vj.z; sJ[r][c4 + 3] = vj.w;
        }
    }
    __syncthreads();
    float eb2v = eb2[0];
#pragma unroll
    for (int pz = 0; pz < 4; ++pz) {
        int e = t + pz * 256;
        int ti = e >> 5, tj = e & 31;
        int i = i0 + ti, j = j0 + tj;
        float sij = 0.f, sji = 0.f;
#pragma unroll
        for (int k = 0; k < 32; ++k) {
            sij = fmaf(fmaxf(sI[ti][k] + sJ[tj][32 + k], 0.f), w2[k], sij);
            sji = fmaf(fmaxf(sJ[tj][k] + sI[ti][32 + k], 0.f), w2[k], sji);
        }
        bool ok = (i != j) && (mask[b * NN + i] > 0.f) && (mask[b * NN + j] > 0.f);
        sV[ti][tj] = ok ? expf(0.5f * (sij + sji) + eb2v) : 0.f;
    }
    __syncthreads();
#pragma unroll
    for (int pz = 0; pz < 4; ++pz) {
        int r = (t >> 5) + pz * 8, c = t & 31;
        // (i0+r, j0+c) from sV[r][c]; transposed (j0+r, i0+c) from sV[c][r]
        float v1 = sV[r][c];
        float v2 = sV[c][r];
        ushort_t h1 = f2bf(v1), l1 = f2bf(v1 - bf2f(h1));
        ushort_t h2 = f2bf(v2), l2 = f2bf(v2 - bf2f(h2));
        size_t o1 = ((size_t)(b * NN + i0 + r)) * NN + j0 + c;
        size_t o2 = ((size_t)(b * NN + j0 + r)) * NN + i0 + c;
        APh[o1] = h1; APl[o1] = l1;
        APh[o2] = h2; APl[o2] = l2;
    }
}

// ---------------------------------------------------------------------------
// Kernel 3: column sums (deg) for A (raw fp32) and AP (hi+lo). For the A half,
// also emit A_hi/A_lo bf16 (we're reading every element anyway).
// grid (2 col-halves, 64 = b*8+rowslice, 2 which)
// ---------------------------------------------------------------------------
__global__ __launch_bounds__(256) void colsum_conv(
    const float* __restrict__ A, const ushort_t* __restrict__ APh,
    const ushort_t* __restrict__ APl, ushort_t* __restrict__ Ah,
    ushort_t* __restrict__ Al, float* __restrict__ dsum)
{
    int which = blockIdx.z;
    int b = blockIdx.y >> 3, rs = blockIdx.y & 7;
    int k = blockIdx.x * 256 + threadIdx.x;
    size_t base = ((size_t)b * NN + rs * 64) * NN + k;
    float s = 0.f;
    if (which == 0) {
#pragma unroll 4
        for (int i = 0; i < 64; ++i) {
            size_t idx = base + (size_t)i * NN;
            float a = A[idx];
            s += a;
            ushort_t h = f2bf(a);
            Ah[idx] = h;
            Al[idx] = f2bf(a - bf2f(h));
        }
    } else {
#pragma unroll 4
        for (int i = 0; i < 64; ++i) {
            size_t idx = base + (size_t)i * NN;
            s += bf2f(APh[idx]) + bf2f(APl[idx]);
        }
    }
    atomicAdd(&dsum[which * (NB * NN) + b * NN + k], s);
}

// ---------------------------------------------------------------------------
// Kernel 4: P = d .* (h @ [W0|W1]); output TRANSPOSED per batch as bf16 hi/lo:
// PT[b][c(128)][i(512)].  M=4096 rows, BM=16, 256 blocks.
// ---------------------------------------------------------------------------
__global__ __launch_bounds__(256) void pre_gemmT(
    const float* __restrict__ h, const float* __restrict__ gw,
    const float* __restrict__ dsum, ushort_t* __restrict__ PTh,
    ushort_t* __restrict__ PTl, int Cin)
{
    __shared__ float sH[32][17];
    __shared__ float sW[32][132];
    __shared__ __align__(16) ushort_t sTh[128][24];
    __shared__ __align__(16) ushort_t sTl[128][24];
    int r0 = blockIdx.x * 16;
    int t = threadIdx.x;
    int tx = t & 31, ty = t >> 5;
    float acc0[4] = {0.f, 0.f, 0.f, 0.f};
    float acc1[4] = {0.f, 0.f, 0.f, 0.f};
    for (int k0 = 0; k0 < Cin; k0 += 32) {
        {
            int kk = (t & 15) * 2, r = t >> 4;
            float2 v = *(const float2*)(h + (size_t)(r0 + r) * Cin + k0 + kk);
            sH[kk][r] = v.x; sH[kk + 1][r] = v.y;
        }
        {
            int c4 = (t & 31) * 4;
            int half = c4 >> 6, cc = c4 & 63;
#pragma unroll
            for (int rr = 0; rr < 4; ++rr) {
                int kk = (t >> 5) + rr * 8;
                *(float4*)&sW[kk][c4] =
                    *(const float4*)(gw + (size_t)(half * Cin + k0 + kk) * 64 + cc);
            }
        }
        __syncthreads();
#pragma unroll
        for (int k = 0; k < 32; ++k) {
            float a0 = sH[k][ty * 2];
            float a1 = sH[k][ty * 2 + 1];
            float4 w = *(const float4*)&sW[k][tx * 4];
            acc0[0] = fmaf(a0, w.x, acc0[0]); acc0[1] = fmaf(a0, w.y, acc0[1]);
            acc0[2] = fmaf(a0, w.z, acc0[2]); acc0[3] = fmaf(a0, w.w, acc0[3]);
            acc1[0] = fmaf(a1, w.x, acc1[0]); acc1[1] = fmaf(a1, w.y, acc1[1]);
            acc1[2] = fmaf(a1, w.z, acc1[2]); acc1[3] = fmaf(a1, w.w, acc1[3]);
        }
        __syncthreads();
    }
    // scale by d (rsqrt inline), split hi/lo, stage transposed in LDS
    int c4 = tx * 4;
    const float* draw = dsum + ((c4 >= 64) ? (NB * NN) : 0);
#pragma unroll
    for (int r = 0; r < 2; ++r) {
        int rl = ty * 2 + r;
        int row = r0 + rl;
        float d = rsqrtf(draw[row] + 1.0f + 1e-5f);
        float* ap = (r == 0) ? acc0 : acc1;
#pragma unroll
        for (int n = 0; n < 4; ++n) {
            float v = d * ap[n];
            ushort_t hh = f2bf(v);
            sTh[c4 + n][rl] = hh;
            sTl[c4 + n][rl] = f2bf(v - bf2f(hh));
        }
    }
    __syncthreads();
    // write out: 16 shorts per (array, c) row, coalesced-ish
    {
        int arr = t >> 7, c = t & 127;
        int bb = r0 >> 9, ibase = r0 & (NN - 1);
        const ushort_t* src = arr ? &sTl[c][0] : &sTh[c][0];
        ushort_t* dst = (arr ? PTl : PTh) + ((size_t)(bb * 128 + c)) * NN + ibase;
        *(short8*)dst = *(const short8*)src;
        *(short8*)(dst + 8) = *(const short8*)(src + 8);
    }
}

// ---------------------------------------------------------------------------
// Kernel 5: fused dual-Laplacian GEMM via bf16 MFMA (hi/lo 3-product split).
// Computes C^T tiles: D[c][i] = sum_k PT[c][k] * Amat[i][k].
// Block: 16 rows (i) x 128 c (both laps), K=512. 4 waves x 2 c-tiles each.
// ---------------------------------------------------------------------------
__global__ __launch_bounds__(256) void fused_mfma(
    const ushort_t* __restrict__ Ah, const ushort_t* __restrict__ Al,
    const ushort_t* __restrict__ APh, const ushort_t* __restrict__ APl,
    const ushort_t* __restrict__ PTh, const ushort_t* __restrict__ PTl,
    const float* __restrict__ dsum, const float* __restrict__ bias,
    const float* __restrict__ mask, float* __restrict__ Hout)
{
    __shared__ __align__(16) ushort_t sA[4][16][72];    // Ah, Al, APh, APl tiles
    __shared__ __align__(16) ushort_t sP[2][128][72];   // PT hi, lo tiles
    int b = blockIdx.y, i0 = blockIdx.x * 16;
    int t = threadIdx.x;
    int lane = t & 63, w = t >> 6;
    int quad = lane >> 4, m16 = lane & 15;
    float4v acc0 = {0.f, 0.f, 0.f, 0.f};
    float4v acc1 = {0.f, 0.f, 0.f, 0.f};

    const ushort_t* asrc0 = (t >> 6) == 0 ? Ah : ((t >> 6) == 1 ? Al : ((t >> 6) == 2 ? APh : APl));
    int sid = t & 63;                      // staging id within array
    int sr = sid >> 2;                     // wait: 128 chunks per array / 64 threads = 2
    (void)sr;

    for (int k0 = 0; k0 < NN; k0 += 64) {
        __syncthreads();
        {   // stage A tiles: 4 arrays x 16 rows x 64 k; thread -> 2 b128 chunks
            int arr = t >> 6, id = t & 63;
#pragma unroll
            for (int cc = 0; cc < 2; ++cc) {
                int chunk = id + cc * 64;           // [0,128)
                int r = chunk >> 3, q = chunk & 7;
                const ushort_t* g = asrc0 + ((size_t)(b * NN + i0 + r)) * NN + k0 + q * 8;
                *(short8*)&sA[arr][r][q * 8] = *(const short8*)g;
            }
            // stage PT tiles: 2 arrays x 128 c x 64 k; thread -> 4 chunks each arr
            int c = t >> 1, qb = t & 1;
            const ushort_t* gh = PTh + ((size_t)(b * 128 + c)) * NN + k0;
            const ushort_t* gl = PTl + ((size_t)(b * 128 + c)) * NN + k0;
#pragma unroll
            for (int cc = 0; cc < 4; ++cc) {
                int q = qb + cc * 2;
                *(short8*)&sP[0][c][q * 8] = *(const short8*)(gh + q * 8);
                *(short8*)&sP[1][c][q * 8] = *(const short8*)(gl + q * 8);
            }
        }
        __syncthreads();
#pragma unroll
        for (int kh = 0; kh < 2; ++kh) {
            int ko = kh * 32 + quad * 8;
            short8 p0h = *(const short8*)&sP[0][w * 16 + m16][ko];
            short8 p0l = *(const short8*)&sP[1][w * 16 + m16][ko];
            short8 p1h = *(const short8*)&sP[0][64 + w * 16 + m16][ko];
            short8 p1l = *(const short8*)&sP[1][64 + w * 16 + m16][ko];
            short8 a0h = *(const short8*)&sA[0][m16][ko];
            short8 a0l = *(const short8*)&sA[1][m16][ko];
            short8 a1h = *(const short8*)&sA[2][m16][ko];
            short8 a1l = *(const short8*)&sA[3][m16][ko];
            acc0 = __builtin_amdgcn_mfma_f32_16x16x32_bf16(p0h, a0h, acc0, 0, 0, 0);
            acc0 = __builtin_amdgcn_mfma_f32_16x16x32_bf16(p0h, a0l, acc0, 0, 0, 0);
            acc0 = __builtin_amdgcn_mfma_f32_16x16x32_bf16(p0l, a0h, acc0, 0, 0, 0);
            acc1 = __builtin_amdgcn_mfma_f32_16x16x32_bf16(p1h, a1h, acc1, 0, 0, 0);
            acc1 = __builtin_amdgcn_mfma_f32_16x16x32_bf16(p1h, a1l, acc1, 0, 0, 0);
            acc1 = __builtin_amdgcn_mfma_f32_16x16x32_bf16(p1l, a1h, acc1, 0, 0, 0);
        }
    }
    // epilogue: lane holds i = i0+m16 (n-dim), c = w*16 + quad*4 + reg (m-dim)
    int gi = b * NN + i0 + m16;
    float d0 = rsqrtf(dsum[gi] + 1.0f + 1e-5f);
    float d1 = rsqrtf(dsum[NB * NN + gi] + 1.0f + 1e-5f);
    float mv = mask[gi];
    int cb = w * 16 + quad * 4;
    float4 o;
    float* op = &o.x;
#pragma unroll
    for (int r = 0; r < 4; ++r) {
        int c = cb + r;
        size_t p0idx = ((size_t)(b * 128 + c)) * NN + i0 + m16;
        size_t p1idx = ((size_t)(b * 128 + 64 + c)) * NN + i0 + m16;
        float p0 = bf2f(PTh[p0idx]) + bf2f(PTl[p0idx]);
        float p1 = bf2f(PTh[p1idx]) + bf2f(PTl[p1idx]);
        op[r] = fmaxf((d0 * (acc0[r] + p0) + d1 * (acc1[r] + p1) + bias[c]) * mv, 0.f);
    }
    *(float4*)&Hout[(size_t)gi * 64 + cb] = o;
}

// ---------------------------------------------------------------------------
// Kernel 6: g[b,o] = max_i H[b,i,o]; out = g @ fcw + fcb
// ---------------------------------------------------------------------------
__global__ __launch_bounds__(256) void final_fc(
    const float* __restrict__ H, const float* __restrict__ fcw,
    const float* __restrict__ fcb, float* __restrict__ out)
{
    __shared__ float red[4][64];
    __shared__ float g[64];
    int b = blockIdx.x;
    int o = threadIdx.x & 63, seg = threadIdx.x >> 6;
    const float* Hb = H + (size_t)b * NN * 64;
    float mx = -INFINITY;
    for (int i = seg; i < NN; i += 4) mx = fmaxf(mx, Hb[(size_t)i * 64 + o]);
    red[seg][o] = mx;
    __syncthreads();
    if (seg == 0)
        g[o] = fmaxf(fmaxf(red[0][o], red[1][o]), fmaxf(red[2][o], red[3][o]));
    __syncthreads();
    if (threadIdx.x < 2) {
        float acc = fcb[threadIdx.x];
        for (int k = 0; k < 64; ++k) acc = fmaf(g[k], fcw[k * 2 + threadIdx.x], acc);
        out[b * 2 + threadIdx.x] = acc;
    }
}

extern "C" void kernel_launch(void* const* d_in, const int* in_sizes, int n_in,
                              void* d_out, int out_size, void* d_ws, size_t ws_size,
                              hipStream_t stream)
{
    const float* x    = (const float*)d_in[0];
    const float* A    = (const float*)d_in[1];
    const float* mask = (const float*)d_in[2];
    const float* ew1  = (const float*)d_in[3];
    const float* eb1  = (const float*)d_in[4];
    const float* ew2  = (const float*)d_in[5];
    const float* eb2  = (const float*)d_in[6];
    const float* gw0  = (const float*)d_in[7];
    const float* gb0  = (const float*)d_in[8];
    const float* gw1  = (const float*)d_in[9];
    const float* gb1  = (const float*)d_in[10];
    const float* gw2  = (const float*)d_in[11];
    const float* gb2  = (const float*)d_in[12];
    const float* fcw  = (const float*)d_in[13];
    const float* fcb  = (const float*)d_in[14];
    float* out = (float*)d_out;
    char* ws = (char*)d_ws;

    const size_t NEL = (size_t)NB * NN * NN;      // 2,097,152
    float*    xab  = (float*)ws;                       ws += 262144 * 4;
    ushort_t* APh  = (ushort_t*)ws;                    ws += NEL * 2;
    ushort_t* APl  = (ushort_t*)ws;                    ws += NEL * 2;
    ushort_t* Ahs  = (ushort_t*)ws;                    ws += NEL * 2;
    ushort_t* Als  = (ushort_t*)ws;                    ws += NEL * 2;
    float*    dsum = (float*)ws;                       ws += 8192 * 4;
    ushort_t* PTh  = (ushort_t*)ws;                    ws += 524288 * 2;
    ushort_t* PTl  = (ushort_t*)ws;                    ws += 524288 * 2;
    float*    hA   = (float*)ws;                       ws += 262144 * 4;
    float*    hB   = (float*)ws;                       ws += 262144 * 4;
    // total ~24.4 MB

    xaxb_gemm  <<<256, 256, 0, stream>>>(x, ew1, eb1, xab, dsum);
    edge_scores<<<dim3(136, 1, NB), 256, 0, stream>>>(xab, ew2, eb2, mask, APh, APl);
    colsum_conv<<<dim3(2, 64, 2), 256, 0, stream>>>(A, APh, APl, Ahs, Als, dsum);

    // layer 0
    pre_gemmT <<<256, 256, 0, stream>>>(x, gw0, dsum, PTh, PTl, 256);
    fused_mfma<<<dim3(32, NB), 256, 0, stream>>>(Ahs, Als, APh, APl, PTh, PTl,
                                                 dsum, gb0, mask, hA);
    // layer 1
    pre_gemmT <<<256, 256, 0, stream>>>(hA, gw1, dsum, PTh, PTl, 64);
    fused_mfma<<<dim3(32, NB), 256, 0, stream>>>(Ahs, Als, APh, APl, PTh, PTl,
                                                 dsum, gb1, mask, hB);
    // layer 2
    pre_gemmT <<<256, 256, 0, stream>>>(hB, gw2, dsum, PTh, PTl, 64);
    fused_mfma<<<dim3(32, NB), 256, 0, stream>>>(Ahs, Als, APh, APl, PTh, PTl,
                                                 dsum, gb2, mask, hA);

    final_fc<<<NB, 256, 0, stream>>>(hA, fcw, fcb, out);
}

// Round 4
// 195.676 us; speedup vs baseline: 1.6894x; 1.1606x over previous
//
#include <hip/hip_runtime.h>
#include <hip/hip_bf16.h>
#include <math.h>

#define NB 8
#define NN 512
#define NC 256
#define HID 32

typedef __attribute__((ext_vector_type(8))) short short8;
typedef __attribute__((ext_vector_type(4))) float float4v;
typedef unsigned short ushort_t;

__device__ __forceinline__ ushort_t f2bf(float x) {
    unsigned u = __float_as_uint(x);
    return (ushort_t)((u + 0x7fffu + ((u >> 16) & 1u)) >> 16);
}
__device__ __forceinline__ float bf2f(ushort_t h) {
    return __uint_as_float(((unsigned)h) << 16);
}

// ---------------------------------------------------------------------------
// Kernel 1: xab = x @ [wa|wb] (+eb1 on wb half). Also zeroes dsum (blocks<32).
// ---------------------------------------------------------------------------
__global__ __launch_bounds__(256) void xaxb_gemm(
    const float* __restrict__ x, const float* __restrict__ ew1,
    const float* __restrict__ eb1, float* __restrict__ xab,
    float* __restrict__ dsum)
{
    __shared__ float sX[32][17];
    __shared__ float sW[32][68];
    int t = threadIdx.x;
    if (blockIdx.x < 32) dsum[blockIdx.x * 256 + t] = 0.f;   // zero-init degrees
    int r0 = blockIdx.x * 16;
    int tx = t & 15, ty = t >> 4;
    float acc[4] = {0.f, 0.f, 0.f, 0.f};
    for (int k0 = 0; k0 < NC; k0 += 32) {
        {
            int kk = (t & 15) * 2, r = t >> 4;
            float2 v = *(const float2*)(x + (size_t)(r0 + r) * NC + k0 + kk);
            sX[kk][r] = v.x; sX[kk + 1][r] = v.y;
        }
        {
            int c4 = (t & 15) * 4;
            int half = c4 >> 5, cc = c4 & 31;
#pragma unroll
            for (int rr = 0; rr < 2; ++rr) {
                int kk = (t >> 4) + rr * 16;
                *(float4*)&sW[kk][c4] =
                    *(const float4*)(ew1 + (size_t)(half * NC + k0 + kk) * HID + cc);
            }
        }
        __syncthreads();
#pragma unroll
        for (int k = 0; k < 32; ++k) {
            float a = sX[k][ty];
            float4 w = *(const float4*)&sW[k][tx * 4];
            acc[0] = fmaf(a, w.x, acc[0]); acc[1] = fmaf(a, w.y, acc[1]);
            acc[2] = fmaf(a, w.z, acc[2]); acc[3] = fmaf(a, w.w, acc[3]);
        }
        __syncthreads();
    }
    int c4 = tx * 4;
    float4 o; o.x = acc[0]; o.y = acc[1]; o.z = acc[2]; o.w = acc[3];
    if (c4 >= 32) {
        o.x += eb1[c4 - 32]; o.y += eb1[c4 - 31];
        o.z += eb1[c4 - 30]; o.w += eb1[c4 - 29];
    }
    *(float4*)&xab[(size_t)(r0 + ty) * 64 + c4] = o;
}

// ---------------------------------------------------------------------------
// Kernel 2: edge scores -> AP as bf16 (hi only), symmetric write via LDS
// ---------------------------------------------------------------------------
__global__ __launch_bounds__(256) void edge_scores(
    const float* __restrict__ xab, const float* __restrict__ ew2,
    const float* __restrict__ eb2, const float* __restrict__ mask,
    ushort_t* __restrict__ APh)
{
    __shared__ float sI[32][65], sJ[32][65];
    __shared__ float sV[32][33];
    __shared__ float w2[32];
    int b = blockIdx.z;
    int p = blockIdx.x;
    int X = 0;
    while ((X + 1) * 16 - ((X + 1) * X) / 2 <= p) ++X;
    int Y = X + (p - (X * 16 - (X * (X - 1)) / 2));
    int i0 = X * 32, j0 = Y * 32;
    int t = threadIdx.x;
    if (t < 32) w2[t] = ew2[t];
    {
        int c4 = (t & 15) * 4;
#pragma unroll
        for (int rr = 0; rr < 2; ++rr) {
            int r = (t >> 4) + rr * 16;
            float4 vi = *(const float4*)(xab + ((size_t)(b * NN + i0 + r)) * 64 + c4);
            float4 vj = *(const float4*)(xab + ((size_t)(b * NN + j0 + r)) * 64 + c4);
            sI[r][c4] = vi.x; sI[r][c4 + 1] = vi.y; sI[r][c4 + 2] = vi.z; sI[r][c4 + 3] = vi.w;
            sJ[r][c4] = vj.x; sJ[r][c4 + 1] = vj.y; sJ[r][c4 + 2] = vj.z; sJ[r][c4 + 3] = vj.w;
        }
    }
    __syncthreads();
    float eb2v = eb2[0];
#pragma unroll
    for (int pz = 0; pz < 4; ++pz) {
        int e = t + pz * 256;
        int ti = e >> 5, tj = e & 31;
        int i = i0 + ti, j = j0 + tj;
        float sij = 0.f, sji = 0.f;
#pragma unroll
        for (int k = 0; k < 32; ++k) {
            sij = fmaf(fmaxf(sI[ti][k] + sJ[tj][32 + k], 0.f), w2[k], sij);
            sji = fmaf(fmaxf(sJ[tj][k] + sI[ti][32 + k], 0.f), w2[k], sji);
        }
        bool ok = (i != j) && (mask[b * NN + i] > 0.f) && (mask[b * NN + j] > 0.f);
        sV[ti][tj] = ok ? expf(0.5f * (sij + sji) + eb2v) : 0.f;
    }
    __syncthreads();
#pragma unroll
    for (int pz = 0; pz < 4; ++pz) {
        int r = (t >> 5) + pz * 8, c = t & 31;
        float v1 = sV[r][c];
        float v2 = sV[c][r];
        size_t o1 = ((size_t)(b * NN + i0 + r)) * NN + j0 + c;
        size_t o2 = ((size_t)(b * NN + j0 + r)) * NN + i0 + c;
        APh[o1] = f2bf(v1);
        APh[o2] = f2bf(v2);
    }
}

// ---------------------------------------------------------------------------
// Kernel 3: column sums (degrees). which==0: sum fp32 A, also emit Ah bf16.
//           which==1: sum APh (bf16).
// ---------------------------------------------------------------------------
__global__ __launch_bounds__(256) void colsum_conv(
    const float* __restrict__ A, const ushort_t* __restrict__ APh,
    ushort_t* __restrict__ Ah, float* __restrict__ dsum)
{
    int which = blockIdx.z;
    int b = blockIdx.y >> 3, rs = blockIdx.y & 7;
    int k = blockIdx.x * 256 + threadIdx.x;
    size_t base = ((size_t)b * NN + rs * 64) * NN + k;
    float s = 0.f;
    if (which == 0) {
#pragma unroll 4
        for (int i = 0; i < 64; ++i) {
            size_t idx = base + (size_t)i * NN;
            float a = A[idx];
            s += a;
            Ah[idx] = f2bf(a);
        }
    } else {
#pragma unroll 4
        for (int i = 0; i < 64; ++i) {
            size_t idx = base + (size_t)i * NN;
            s += bf2f(APh[idx]);
        }
    }
    atomicAdd(&dsum[which * (NB * NN) + b * NN + k], s);
}

// ---------------------------------------------------------------------------
// Kernel 4: P = d .* (h @ [W0|W1]); output TRANSPOSED per batch as bf16 hi/lo:
// PT[b][c(128)][i(512)].  M=4096 rows, BM=16, 256 blocks.
// ---------------------------------------------------------------------------
__global__ __launch_bounds__(256) void pre_gemmT(
    const float* __restrict__ h, const float* __restrict__ gw,
    const float* __restrict__ dsum, ushort_t* __restrict__ PTh,
    ushort_t* __restrict__ PTl, int Cin)
{
    __shared__ float sH[32][17];
    __shared__ float sW[32][132];
    __shared__ __align__(16) ushort_t sTh[128][24];
    __shared__ __align__(16) ushort_t sTl[128][24];
    int r0 = blockIdx.x * 16;
    int t = threadIdx.x;
    int tx = t & 31, ty = t >> 5;
    float acc0[4] = {0.f, 0.f, 0.f, 0.f};
    float acc1[4] = {0.f, 0.f, 0.f, 0.f};
    for (int k0 = 0; k0 < Cin; k0 += 32) {
        {
            int kk = (t & 15) * 2, r = t >> 4;
            float2 v = *(const float2*)(h + (size_t)(r0 + r) * Cin + k0 + kk);
            sH[kk][r] = v.x; sH[kk + 1][r] = v.y;
        }
        {
            int c4 = (t & 31) * 4;
            int half = c4 >> 6, cc = c4 & 63;
#pragma unroll
            for (int rr = 0; rr < 4; ++rr) {
                int kk = (t >> 5) + rr * 8;
                *(float4*)&sW[kk][c4] =
                    *(const float4*)(gw + (size_t)(half * Cin + k0 + kk) * 64 + cc);
            }
        }
        __syncthreads();
#pragma unroll
        for (int k = 0; k < 32; ++k) {
            float a0 = sH[k][ty * 2];
            float a1 = sH[k][ty * 2 + 1];
            float4 w = *(const float4*)&sW[k][tx * 4];
            acc0[0] = fmaf(a0, w.x, acc0[0]); acc0[1] = fmaf(a0, w.y, acc0[1]);
            acc0[2] = fmaf(a0, w.z, acc0[2]); acc0[3] = fmaf(a0, w.w, acc0[3]);
            acc1[0] = fmaf(a1, w.x, acc1[0]); acc1[1] = fmaf(a1, w.y, acc1[1]);
            acc1[2] = fmaf(a1, w.z, acc1[2]); acc1[3] = fmaf(a1, w.w, acc1[3]);
        }
        __syncthreads();
    }
    int c4 = tx * 4;
    const float* draw = dsum + ((c4 >= 64) ? (NB * NN) : 0);
#pragma unroll
    for (int r = 0; r < 2; ++r) {
        int rl = ty * 2 + r;
        int row = r0 + rl;
        float d = rsqrtf(draw[row] + 1.0f + 1e-5f);
        float* ap = (r == 0) ? acc0 : acc1;
#pragma unroll
        for (int n = 0; n < 4; ++n) {
            float v = d * ap[n];
            ushort_t hh = f2bf(v);
            sTh[c4 + n][rl] = hh;
            sTl[c4 + n][rl] = f2bf(v - bf2f(hh));
        }
    }
    __syncthreads();
    {
        int arr = t >> 7, c = t & 127;
        int bb = r0 >> 9, ibase = r0 & (NN - 1);
        const ushort_t* src = arr ? &sTl[c][0] : &sTh[c][0];
        ushort_t* dst = (arr ? PTl : PTh) + ((size_t)(bb * 128 + c)) * NN + ibase;
        *(short8*)dst = *(const short8*)src;
        *(short8*)(dst + 8) = *(const short8*)(src + 8);
    }
}

// ---------------------------------------------------------------------------
// Kernel 5: fused dual-Laplacian GEMM via bf16 MFMA, 2-product (Ah*(Ph+Pl)).
// Grid (32 i-tiles, 2 col-halves, 8 batches) = 512 blocks, 4 waves each.
// Wave w: lap = w>>1, ctile = w&1 -> P-row tile l = w*16 + m16.
// D^T tiles: D[c][i] = sum_k PT[c][k] * Amat[i][k]; laps combined via LDS.
// ---------------------------------------------------------------------------
__global__ __launch_bounds__(256) void fused_mfma(
    const ushort_t* __restrict__ Ah, const ushort_t* __restrict__ APh,
    const ushort_t* __restrict__ PTh, const ushort_t* __restrict__ PTl,
    const float* __restrict__ dsum, const float* __restrict__ bias,
    const float* __restrict__ mask, float* __restrict__ Hout)
{
    __shared__ __align__(16) ushort_t sA[2][16][72];    // [lap][i][k]
    __shared__ __align__(16) ushort_t sPh[64][72];      // [l][k]
    __shared__ __align__(16) ushort_t sPl[64][72];
    __shared__ float sRed[2][32][17];                   // [lap][c_in32][i]
    int b = blockIdx.z, ch = blockIdx.y, i0 = blockIdx.x * 16;
    int t = threadIdx.x;
    int lane = t & 63, w = t >> 6;
    int quad = lane >> 4, m16 = lane & 15;
    int lap = w >> 1;
    float4v acc = {0.f, 0.f, 0.f, 0.f};

    // staging roles (constant across k0 loop)
    int sa_arr = t >> 7, sa_id = t & 127;
    int sa_r = sa_id >> 3, sa_q = sa_id & 7;
    const ushort_t* sa_src = (sa_arr ? APh : Ah)
        + ((size_t)(b * NN + i0 + sa_r)) * NN + sa_q * 8;

    for (int k0 = 0; k0 < NN; k0 += 64) {
        __syncthreads();
        // stage A tiles: 2 arrays x 16 rows x 64 k = 256 chunks, 1/thread
        *(short8*)&sA[sa_arr][sa_r][sa_q * 8] = *(const short8*)(sa_src + k0);
        // stage P tiles: hi/lo x 64 l x 8 q = 1024 chunks, 4/thread
#pragma unroll
        for (int cc = 0; cc < 4; ++cc) {
            int chunk = t + cc * 256;
            int hl = chunk >> 9, l = (chunk >> 3) & 63, q = chunk & 7;
            int colg = (l >> 5) * 64 + ch * 32 + (l & 31);
            const ushort_t* src = (hl ? PTl : PTh)
                + ((size_t)(b * 128 + colg)) * NN + k0 + q * 8;
            if (hl) *(short8*)&sPl[l][q * 8] = *(const short8*)src;
            else    *(short8*)&sPh[l][q * 8] = *(const short8*)src;
        }
        __syncthreads();
#pragma unroll
        for (int kh = 0; kh < 2; ++kh) {
            int ko = kh * 32 + quad * 8;
            short8 ph = *(const short8*)&sPh[w * 16 + m16][ko];
            short8 pl = *(const short8*)&sPl[w * 16 + m16][ko];
            short8 av = *(const short8*)&sA[lap][m16][ko];
            acc = __builtin_amdgcn_mfma_f32_16x16x32_bf16(ph, av, acc, 0, 0, 0);
            acc = __builtin_amdgcn_mfma_f32_16x16x32_bf16(pl, av, acc, 0, 0, 0);
        }
    }
    // epilogue: lane covers i = i0+m16, cols c_in32 = (w&1)*16 + quad*4 + r
    int gi = b * NN + i0 + m16;
    float d = rsqrtf(dsum[lap * (NB * NN) + gi] + 1.0f + 1e-5f);
    int cbase = (w & 1) * 16 + quad * 4;
#pragma unroll
    for (int r = 0; r < 4; ++r) {
        int c32 = cbase + r;
        int pcol = lap * 64 + ch * 32 + c32;
        size_t pidx = ((size_t)(b * 128 + pcol)) * NN + i0 + m16;
        float pv = bf2f(PTh[pidx]) + bf2f(PTl[pidx]);
        sRed[lap][c32][m16] = d * (acc[r] + pv);
    }
    __syncthreads();
    // combine laps, bias, relu, mask; 512 outputs / 256 threads
#pragma unroll
    for (int s = 0; s < 2; ++s) {
        int idx = t + s * 256;
        int c32 = idx & 31, i = idx >> 5;
        int gi2 = b * NN + i0 + i;
        float v = (sRed[0][c32][i] + sRed[1][c32][i] + bias[ch * 32 + c32]) * mask[gi2];
        Hout[(size_t)gi2 * 64 + ch * 32 + c32] = fmaxf(v, 0.f);
    }
}

// ---------------------------------------------------------------------------
// Kernel 6: g[b,o] = max_i H[b,i,o]; out = g @ fcw + fcb
// ---------------------------------------------------------------------------
__global__ __launch_bounds__(256) void final_fc(
    const float* __restrict__ H, const float* __restrict__ fcw,
    const float* __restrict__ fcb, float* __restrict__ out)
{
    __shared__ float red[4][64];
    __shared__ float g[64];
    int b = blockIdx.x;
    int o = threadIdx.x & 63, seg = threadIdx.x >> 6;
    const float* Hb = H + (size_t)b * NN * 64;
    float mx = -INFINITY;
    for (int i = seg; i < NN; i += 4) mx = fmaxf(mx, Hb[(size_t)i * 64 + o]);
    red[seg][o] = mx;
    __syncthreads();
    if (seg == 0)
        g[o] = fmaxf(fmaxf(red[0][o], red[1][o]), fmaxf(red[2][o], red[3][o]));
    __syncthreads();
    if (threadIdx.x < 2) {
        float acc = fcb[threadIdx.x];
        for (int k = 0; k < 64; ++k) acc = fmaf(g[k], fcw[k * 2 + threadIdx.x], acc);
        out[b * 2 + threadIdx.x] = acc;
    }
}

extern "C" void kernel_launch(void* const* d_in, const int* in_sizes, int n_in,
                              void* d_out, int out_size, void* d_ws, size_t ws_size,
                              hipStream_t stream)
{
    const float* x    = (const float*)d_in[0];
    const float* A    = (const float*)d_in[1];
    const float* mask = (const float*)d_in[2];
    const float* ew1  = (const float*)d_in[3];
    const float* eb1  = (const float*)d_in[4];
    const float* ew2  = (const float*)d_in[5];
    const float* eb2  = (const float*)d_in[6];
    const float* gw0  = (const float*)d_in[7];
    const float* gb0  = (const float*)d_in[8];
    const float* gw1  = (const float*)d_in[9];
    const float* gb1  = (const float*)d_in[10];
    const float* gw2  = (const float*)d_in[11];
    const float* gb2  = (const float*)d_in[12];
    const float* fcw  = (const float*)d_in[13];
    const float* fcb  = (const float*)d_in[14];
    float* out = (float*)d_out;
    char* ws = (char*)d_ws;

    const size_t NEL = (size_t)NB * NN * NN;      // 2,097,152
    float*    xab  = (float*)ws;                       ws += 262144 * 4;
    ushort_t* APh  = (ushort_t*)ws;                    ws += NEL * 2;
    ushort_t* Ahs  = (ushort_t*)ws;                    ws += NEL * 2;
    float*    dsum = (float*)ws;                       ws += 8192 * 4;
    ushort_t* PTh  = (ushort_t*)ws;                    ws += 524288 * 2;
    ushort_t* PTl  = (ushort_t*)ws;                    ws += 524288 * 2;
    float*    hA   = (float*)ws;                       ws += 262144 * 4;
    float*    hB   = (float*)ws;                       ws += 262144 * 4;
    // total ~14.3 MB

    xaxb_gemm  <<<256, 256, 0, stream>>>(x, ew1, eb1, xab, dsum);
    edge_scores<<<dim3(136, 1, NB), 256, 0, stream>>>(xab, ew2, eb2, mask, APh);
    colsum_conv<<<dim3(2, 64, 2), 256, 0, stream>>>(A, APh, Ahs, dsum);

    // layer 0
    pre_gemmT <<<256, 256, 0, stream>>>(x, gw0, dsum, PTh, PTl, 256);
    fused_mfma<<<dim3(32, 2, NB), 256, 0, stream>>>(Ahs, APh, PTh, PTl,
                                                    dsum, gb0, mask, hA);
    // layer 1
    pre_gemmT <<<256, 256, 0, stream>>>(hA, gw1, dsum, PTh, PTl, 64);
    fused_mfma<<<dim3(32, 2, NB), 256, 0, stream>>>(Ahs, APh, PTh, PTl,
                                                    dsum, gb1, mask, hB);
    // layer 2
    pre_gemmT <<<256, 256, 0, stream>>>(hB, gw2, dsum, PTh, PTl, 64);
    fused_mfma<<<dim3(32, 2, NB), 256, 0, stream>>>(Ahs, APh, PTh, PTl,
                                                    dsum, gb2, mask, hA);

    final_fc<<<NB, 256, 0, stream>>>(hA, fcw, fcb, out);
}

// Round 5
// 182.632 us; speedup vs baseline: 1.8101x; 1.0714x over previous
//
#include <hip/hip_runtime.h>
#include <hip/hip_bf16.h>
#include <math.h>

#define NB 8
#define NN 512
#define NC 256
#define HID 32

typedef __attribute__((ext_vector_type(8))) short short8;
typedef __attribute__((ext_vector_type(4))) float float4v;
typedef unsigned short ushort_t;

__device__ __forceinline__ ushort_t f2bf(float x) {
    unsigned u = __float_as_uint(x);
    return (ushort_t)((u + 0x7fffu + ((u >> 16) & 1u)) >> 16);
}
__device__ __forceinline__ float bf2f(ushort_t h) {
    return __uint_as_float(((unsigned)h) << 16);
}

// ---------------------------------------------------------------------------
// Kernel 1: xab = x @ [wa|wb] (+eb1 on wb half). Also zeroes dsum (blocks<32).
// ---------------------------------------------------------------------------
__global__ __launch_bounds__(256) void xaxb_gemm(
    const float* __restrict__ x, const float* __restrict__ ew1,
    const float* __restrict__ eb1, float* __restrict__ xab,
    float* __restrict__ dsum)
{
    __shared__ float sX[32][17];
    __shared__ float sW[32][68];
    int t = threadIdx.x;
    if (blockIdx.x < 32) dsum[blockIdx.x * 256 + t] = 0.f;   // zero-init degrees
    int r0 = blockIdx.x * 16;
    int tx = t & 15, ty = t >> 4;
    float acc[4] = {0.f, 0.f, 0.f, 0.f};
    for (int k0 = 0; k0 < NC; k0 += 32) {
        {
            int kk = (t & 15) * 2, r = t >> 4;
            float2 v = *(const float2*)(x + (size_t)(r0 + r) * NC + k0 + kk);
            sX[kk][r] = v.x; sX[kk + 1][r] = v.y;
        }
        {
            int c4 = (t & 15) * 4;
            int half = c4 >> 5, cc = c4 & 31;
#pragma unroll
            for (int rr = 0; rr < 2; ++rr) {
                int kk = (t >> 4) + rr * 16;
                *(float4*)&sW[kk][c4] =
                    *(const float4*)(ew1 + (size_t)(half * NC + k0 + kk) * HID + cc);
            }
        }
        __syncthreads();
#pragma unroll
        for (int k = 0; k < 32; ++k) {
            float a = sX[k][ty];
            float4 w = *(const float4*)&sW[k][tx * 4];
            acc[0] = fmaf(a, w.x, acc[0]); acc[1] = fmaf(a, w.y, acc[1]);
            acc[2] = fmaf(a, w.z, acc[2]); acc[3] = fmaf(a, w.w, acc[3]);
        }
        __syncthreads();
    }
    int c4 = tx * 4;
    float4 o; o.x = acc[0]; o.y = acc[1]; o.z = acc[2]; o.w = acc[3];
    if (c4 >= 32) {
        o.x += eb1[c4 - 32]; o.y += eb1[c4 - 31];
        o.z += eb1[c4 - 30]; o.w += eb1[c4 - 29];
    }
    *(float4*)&xab[(size_t)(r0 + ty) * 64 + c4] = o;
}

// ---------------------------------------------------------------------------
// Kernel 2: edge scores -> AP bf16 (symmetric write via LDS), AP column sums
// (atomics into dsum[1], from the sV tile), and for p<128: A->bf16 conversion
// + A column partial sums (atomics into dsum[0]). dsum pre-zeroed by kernel 1.
// ---------------------------------------------------------------------------
__global__ __launch_bounds__(256) void edge_scores(
    const float* __restrict__ xab, const float* __restrict__ ew2,
    const float* __restrict__ eb2, const float* __restrict__ mask,
    const float* __restrict__ A, ushort_t* __restrict__ Ah,
    ushort_t* __restrict__ APh, float* __restrict__ dsum)
{
    __shared__ float sI[32][65], sJ[32][65];
    __shared__ float sV[32][33];
    __shared__ float w2[32];
    int b = blockIdx.z;
    int p = blockIdx.x;
    int X = 0;
    while ((X + 1) * 16 - ((X + 1) * X) / 2 <= p) ++X;
    int Y = X + (p - (X * 16 - (X * (X - 1)) / 2));
    int i0 = X * 32, j0 = Y * 32;
    int t = threadIdx.x;
    if (t < 32) w2[t] = ew2[t];
    {
        int c4 = (t & 15) * 4;
#pragma unroll
        for (int rr = 0; rr < 2; ++rr) {
            int r = (t >> 4) + rr * 16;
            float4 vi = *(const float4*)(xab + ((size_t)(b * NN + i0 + r)) * 64 + c4);
            float4 vj = *(const float4*)(xab + ((size_t)(b * NN + j0 + r)) * 64 + c4);
            sI[r][c4] = vi.x; sI[r][c4 + 1] = vi.y; sI[r][c4 + 2] = vi.z; sI[r][c4 + 3] = vi.w;
            sJ[r][c4] = vj.x; sJ[r][c4 + 1] = vj.y; sJ[r][c4 + 2] = vj.z; sJ[r][c4 + 3] = vj.w;
        }
    }
    __syncthreads();
    float eb2v = eb2[0];
#pragma unroll
    for (int pz = 0; pz < 4; ++pz) {
        int e = t + pz * 256;
        int ti = e >> 5, tj = e & 31;
        int i = i0 + ti, j = j0 + tj;
        float sij = 0.f, sji = 0.f;
#pragma unroll
        for (int k = 0; k < 32; ++k) {
            sij = fmaf(fmaxf(sI[ti][k] + sJ[tj][32 + k], 0.f), w2[k], sij);
            sji = fmaf(fmaxf(sJ[tj][k] + sI[ti][32 + k], 0.f), w2[k], sji);
        }
        bool ok = (i != j) && (mask[b * NN + i] > 0.f) && (mask[b * NN + j] > 0.f);
        sV[ti][tj] = ok ? expf(0.5f * (sij + sji) + eb2v) : 0.f;
    }
    __syncthreads();
    // symmetric bf16 writes
#pragma unroll
    for (int pz = 0; pz < 4; ++pz) {
        int r = (t >> 5) + pz * 8, c = t & 31;
        size_t o1 = ((size_t)(b * NN + i0 + r)) * NN + j0 + c;
        size_t o2 = ((size_t)(b * NN + j0 + r)) * NN + i0 + c;
        APh[o1] = f2bf(sV[r][c]);
        APh[o2] = f2bf(sV[c][r]);
    }
    // AP column sums from this tile (diag tiles contribute once)
    if (t < 32) {
        float s = 0.f;
#pragma unroll
        for (int r = 0; r < 32; ++r) s += sV[r][t];
        atomicAdd(&dsum[(NB * NN) + b * NN + j0 + t], s);
    } else if (t < 64 && X != Y) {
        int c = t - 32;
        float s = 0.f;
#pragma unroll
        for (int j = 0; j < 32; ++j) s += sV[c][j];
        atomicAdd(&dsum[(NB * NN) + b * NN + i0 + c], s);
    }
    // A conversion + A column partial sums: blocks p<128 own rows 4p..4p+3
    if (p < 128) {
        const float* Ar = A + ((size_t)b * NN + 4 * p) * NN;
        ushort_t* Hr = Ah + ((size_t)b * NN + 4 * p) * NN;
        float s0 = 0.f, s1 = 0.f;
#pragma unroll
        for (int rr = 0; rr < 4; ++rr) {
            float a0 = Ar[(size_t)rr * NN + t];
            float a1 = Ar[(size_t)rr * NN + t + 256];
            Hr[(size_t)rr * NN + t] = f2bf(a0);
            Hr[(size_t)rr * NN + t + 256] = f2bf(a1);
            s0 += a0; s1 += a1;
        }
        atomicAdd(&dsum[b * NN + t], s0);
        atomicAdd(&dsum[b * NN + t + 256], s1);
    }
}

// ---------------------------------------------------------------------------
// Kernel 3: P = d .* (h @ [W0|W1]); output TRANSPOSED per batch as bf16:
// PT[b][c(128)][i(512)].  M=4096 rows, BM=16, 256 blocks.
// ---------------------------------------------------------------------------
__global__ __launch_bounds__(256) void pre_gemmT(
    const float* __restrict__ h, const float* __restrict__ gw,
    const float* __restrict__ dsum, ushort_t* __restrict__ PTh, int Cin)
{
    __shared__ float sH[32][17];
    __shared__ float sW[32][132];
    __shared__ __align__(16) ushort_t sTh[128][24];
    int r0 = blockIdx.x * 16;
    int t = threadIdx.x;
    int tx = t & 31, ty = t >> 5;
    float acc0[4] = {0.f, 0.f, 0.f, 0.f};
    float acc1[4] = {0.f, 0.f, 0.f, 0.f};
    for (int k0 = 0; k0 < Cin; k0 += 32) {
        {
            int kk = (t & 15) * 2, r = t >> 4;
            float2 v = *(const float2*)(h + (size_t)(r0 + r) * Cin + k0 + kk);
            sH[kk][r] = v.x; sH[kk + 1][r] = v.y;
        }
        {
            int c4 = (t & 31) * 4;
            int half = c4 >> 6, cc = c4 & 63;
#pragma unroll
            for (int rr = 0; rr < 4; ++rr) {
                int kk = (t >> 5) + rr * 8;
                *(float4*)&sW[kk][c4] =
                    *(const float4*)(gw + (size_t)(half * Cin + k0 + kk) * 64 + cc);
            }
        }
        __syncthreads();
#pragma unroll
        for (int k = 0; k < 32; ++k) {
            float a0 = sH[k][ty * 2];
            float a1 = sH[k][ty * 2 + 1];
            float4 w = *(const float4*)&sW[k][tx * 4];
            acc0[0] = fmaf(a0, w.x, acc0[0]); acc0[1] = fmaf(a0, w.y, acc0[1]);
            acc0[2] = fmaf(a0, w.z, acc0[2]); acc0[3] = fmaf(a0, w.w, acc0[3]);
            acc1[0] = fmaf(a1, w.x, acc1[0]); acc1[1] = fmaf(a1, w.y, acc1[1]);
            acc1[2] = fmaf(a1, w.z, acc1[2]); acc1[3] = fmaf(a1, w.w, acc1[3]);
        }
        __syncthreads();
    }
    int c4 = tx * 4;
    const float* draw = dsum + ((c4 >= 64) ? (NB * NN) : 0);
#pragma unroll
    for (int r = 0; r < 2; ++r) {
        int rl = ty * 2 + r;
        int row = r0 + rl;
        float d = rsqrtf(draw[row] + 1.0f + 1e-5f);
        float* ap = (r == 0) ? acc0 : acc1;
#pragma unroll
        for (int n = 0; n < 4; ++n)
            sTh[c4 + n][rl] = f2bf(d * ap[n]);
    }
    __syncthreads();
    {
        int c = t & 127, half = t >> 7;
        int bb = r0 >> 9, ibase = r0 & (NN - 1);
        ushort_t* dst = PTh + ((size_t)(bb * 128 + c)) * NN + ibase + half * 8;
        *(short8*)dst = *(const short8*)&sTh[c][half * 8];
    }
}

// ---------------------------------------------------------------------------
// Kernel 4: fused dual-Laplacian GEMM via bf16 MFMA (hi-only operands).
// Grid (32 i-tiles, 2 col-halves, 8 batches) = 512 blocks, 4 waves each.
// Wave w: lap = w>>1, ctile = w&1. D^T: D[c][i] = sum_k PT[c][k]*Amat[i][k].
// ---------------------------------------------------------------------------
__global__ __launch_bounds__(256) void fused_mfma(
    const ushort_t* __restrict__ Ah, const ushort_t* __restrict__ APh,
    const ushort_t* __restrict__ PTh, const float* __restrict__ dsum,
    const float* __restrict__ bias, const float* __restrict__ mask,
    float* __restrict__ Hout)
{
    __shared__ __align__(16) ushort_t sA[2][16][72];    // [lap][i][k]
    __shared__ __align__(16) ushort_t sPh[64][72];      // [l][k]
    __shared__ float sRed[2][32][17];                   // [lap][c_in32][i]
    int b = blockIdx.z, ch = blockIdx.y, i0 = blockIdx.x * 16;
    int t = threadIdx.x;
    int lane = t & 63, w = t >> 6;
    int quad = lane >> 4, m16 = lane & 15;
    int lap = w >> 1;
    float4v acc = {0.f, 0.f, 0.f, 0.f};

    // staging roles (constant across k0 loop)
    int sa_arr = t >> 7, sa_id = t & 127;
    int sa_r = sa_id >> 3, sa_q = sa_id & 7;
    const ushort_t* sa_src = (sa_arr ? APh : Ah)
        + ((size_t)(b * NN + i0 + sa_r)) * NN + sa_q * 8;

    for (int k0 = 0; k0 < NN; k0 += 64) {
        __syncthreads();
        // stage A tiles: 2 arrays x 16 rows x 8 q = 256 chunks, 1/thread
        *(short8*)&sA[sa_arr][sa_r][sa_q * 8] = *(const short8*)(sa_src + k0);
        // stage P tile: 64 l x 8 q = 512 chunks, 2/thread
#pragma unroll
        for (int cc = 0; cc < 2; ++cc) {
            int chunk = t + cc * 256;
            int l = chunk >> 3, q = chunk & 7;
            int colg = (l >> 5) * 64 + ch * 32 + (l & 31);
            const ushort_t* src = PTh + ((size_t)(b * 128 + colg)) * NN + k0 + q * 8;
            *(short8*)&sPh[l][q * 8] = *(const short8*)src;
        }
        __syncthreads();
#pragma unroll
        for (int kh = 0; kh < 2; ++kh) {
            int ko = kh * 32 + quad * 8;
            short8 ph = *(const short8*)&sPh[w * 16 + m16][ko];
            short8 av = *(const short8*)&sA[lap][m16][ko];
            acc = __builtin_amdgcn_mfma_f32_16x16x32_bf16(ph, av, acc, 0, 0, 0);
        }
    }
    // epilogue: lane covers i = i0+m16, cols c_in32 = (w&1)*16 + quad*4 + r
    int gi = b * NN + i0 + m16;
    float d = rsqrtf(dsum[lap * (NB * NN) + gi] + 1.0f + 1e-5f);
    int cbase = (w & 1) * 16 + quad * 4;
#pragma unroll
    for (int r = 0; r < 4; ++r) {
        int c32 = cbase + r;
        int pcol = lap * 64 + ch * 32 + c32;
        size_t pidx = ((size_t)(b * 128 + pcol)) * NN + i0 + m16;
        float pv = bf2f(PTh[pidx]);
        sRed[lap][c32][m16] = d * (acc[r] + pv);
    }
    __syncthreads();
    // combine laps, bias, relu, mask; 512 outputs / 256 threads
#pragma unroll
    for (int s = 0; s < 2; ++s) {
        int idx = t + s * 256;
        int c32 = idx & 31, i = idx >> 5;
        int gi2 = b * NN + i0 + i;
        float v = (sRed[0][c32][i] + sRed[1][c32][i] + bias[ch * 32 + c32]) * mask[gi2];
        Hout[(size_t)gi2 * 64 + ch * 32 + c32] = fmaxf(v, 0.f);
    }
}

// ---------------------------------------------------------------------------
// Kernel 5: g[b,o] = max_i H[b,i,o]; out = g @ fcw + fcb
// ---------------------------------------------------------------------------
__global__ __launch_bounds__(256) void final_fc(
    const float* __restrict__ H, const float* __restrict__ fcw,
    const float* __restrict__ fcb, float* __restrict__ out)
{
    __shared__ float red[4][64];
    __shared__ float g[64];
    int b = blockIdx.x;
    int o = threadIdx.x & 63, seg = threadIdx.x >> 6;
    const float* Hb = H + (size_t)b * NN * 64;
    float mx = -INFINITY;
    for (int i = seg; i < NN; i += 4) mx = fmaxf(mx, Hb[(size_t)i * 64 + o]);
    red[seg][o] = mx;
    __syncthreads();
    if (seg == 0)
        g[o] = fmaxf(fmaxf(red[0][o], red[1][o]), fmaxf(red[2][o], red[3][o]));
    __syncthreads();
    if (threadIdx.x < 2) {
        float acc = fcb[threadIdx.x];
        for (int k = 0; k < 64; ++k) acc = fmaf(g[k], fcw[k * 2 + threadIdx.x], acc);
        out[b * 2 + threadIdx.x] = acc;
    }
}

extern "C" void kernel_launch(void* const* d_in, const int* in_sizes, int n_in,
                              void* d_out, int out_size, void* d_ws, size_t ws_size,
                              hipStream_t stream)
{
    const float* x    = (const float*)d_in[0];
    const float* A    = (const float*)d_in[1];
    const float* mask = (const float*)d_in[2];
    const float* ew1  = (const float*)d_in[3];
    const float* eb1  = (const float*)d_in[4];
    const float* ew2  = (const float*)d_in[5];
    const float* eb2  = (const float*)d_in[6];
    const float* gw0  = (const float*)d_in[7];
    const float* gb0  = (const float*)d_in[8];
    const float* gw1  = (const float*)d_in[9];
    const float* gb1  = (const float*)d_in[10];
    const float* gw2  = (const float*)d_in[11];
    const float* gb2  = (const float*)d_in[12];
    const float* fcw  = (const float*)d_in[13];
    const float* fcb  = (const float*)d_in[14];
    float* out = (float*)d_out;
    char* ws = (char*)d_ws;

    const size_t NEL = (size_t)NB * NN * NN;      // 2,097,152
    float*    xab  = (float*)ws;                       ws += 262144 * 4;
    ushort_t* APh  = (ushort_t*)ws;                    ws += NEL * 2;
    ushort_t* Ahs  = (ushort_t*)ws;                    ws += NEL * 2;
    float*    dsum = (float*)ws;                       ws += 8192 * 4;
    ushort_t* PTh  = (ushort_t*)ws;                    ws += 524288 * 2;
    float*    hA   = (float*)ws;                       ws += 262144 * 4;
    float*    hB   = (float*)ws;                       ws += 262144 * 4;
    // total ~12.3 MB

    xaxb_gemm  <<<256, 256, 0, stream>>>(x, ew1, eb1, xab, dsum);
    edge_scores<<<dim3(136, 1, NB), 256, 0, stream>>>(xab, ew2, eb2, mask,
                                                      A, Ahs, APh, dsum);

    // layer 0
    pre_gemmT <<<256, 256, 0, stream>>>(x, gw0, dsum, PTh, 256);
    fused_mfma<<<dim3(32, 2, NB), 256, 0, stream>>>(Ahs, APh, PTh,
                                                    dsum, gb0, mask, hA);
    // layer 1
    pre_gemmT <<<256, 256, 0, stream>>>(hA, gw1, dsum, PTh, 64);
    fused_mfma<<<dim3(32, 2, NB), 256, 0, stream>>>(Ahs, APh, PTh,
                                                    dsum, gb1, mask, hB);
    // layer 2
    pre_gemmT <<<256, 256, 0, stream>>>(hB, gw2, dsum, PTh, 64);
    fused_mfma<<<dim3(32, 2, NB), 256, 0, stream>>>(Ahs, APh, PTh,
                                                    dsum, gb2, mask, hA);

    final_fc<<<NB, 256, 0, stream>>>(hA, fcw, fcb, out);
}